// Round 2
// baseline (29.439 us; speedup 1.0000x reference)
//
#include <hip/hip_runtime.h>
#include <hip/hip_bf16.h>

#define FDIM 1024
#define KNZ 32
#define NROWS 2048
#define RB 8          // rows per block
#define TPB 1024      // threads per block == FDIM (o = tid)
#define EPSV 1e-6f

static_assert(TPB == FDIM, "o = tid mapping requires TPB == FDIM");
static_assert(NROWS % RB == 0, "rows divide");

// granule swizzle: spreads structured f-sequences across the 8 bank-quads
__device__ __forceinline__ unsigned int swz(unsigned int i) {
  return i ^ ((i >> 3) & 7u);
}

__device__ __forceinline__ unsigned int f2bf(float f) {
  unsigned int u = __float_as_uint(f);
  u += 0x7fffu + ((u >> 16) & 1u);   // RNE
  return u >> 16;
}

__device__ __forceinline__ unsigned int pack2bf(float a, float b) {
  return f2bf(a) | (f2bf(b) << 16);
}

// Fused table: pc[k*FDIM+o] = { off | w1bf<<16 , off | w2bf<<16 }.
// Stage 1 loads the uint2 (coalesced); stage 2 replays word .y from registers.
__global__ void geo_prep(const int* __restrict__ idx,
                         const float* __restrict__ w1,
                         const float* __restrict__ w2,
                         uint2* __restrict__ pc) {
  __shared__ int   li[16 * 33];
  __shared__ float l1[16 * 33];
  __shared__ float l2[16 * 33];
  const int t = threadIdx.x;       // 256 threads
  const int o0 = blockIdx.x * 16;  // 16 outputs per block
  #pragma unroll
  for (int e = 0; e < 2; ++e) {
    int j = t + e * 256;           // coalesced global read of [o][k]
    int ol = j >> 5, k = j & 31;
    int g = o0 * KNZ + j;
    li[ol * 33 + k] = idx[g];
    l1[ol * 33 + k] = w1[g];
    l2[ol * 33 + k] = w2[g];
  }
  __syncthreads();
  #pragma unroll
  for (int e = 0; e < 2; ++e) {
    int j = t + e * 256;
    int ol = j & 15, k = j >> 4;   // consecutive t -> consecutive o: coalesced write
    unsigned off = swz((unsigned)li[ol * 33 + k]);
    pc[k * FDIM + o0 + ol] = make_uint2(off | (f2bf(l1[ol * 33 + k]) << 16),
                                        off | (f2bf(l2[ol * 33 + k]) << 16));
  }
}

template <bool TR>
__global__ __launch_bounds__(TPB)
void geo_main(const float* __restrict__ x, const float* __restrict__ norm_w,
              const float* __restrict__ b1, const float* __restrict__ amp,
              const float* __restrict__ freq, const float* __restrict__ decay,
              const float* __restrict__ b2, const float* __restrict__ alpha,
              const uint2* __restrict__ pc,
              const int* __restrict__ idx, const float* __restrict__ w1,
              const float* __restrict__ w2, float* __restrict__ out) {
  // granule f holds rows 0..7 of feature f as 8 bf16 (dword d = rows 2d|2d+1)
  __shared__ uint4 h_lds[FDIM];            // 16 KB, holds g*x (rs applied later)
  __shared__ uint4 s_lds[FDIM];            // 16 KB
  __shared__ float red[(TPB / 64) * RB];   // 128 per-wave row partials

  const int tid = threadIdx.x;
  const int lane = tid & 63;
  const int wid = tid >> 6;
  const int r0 = blockIdx.x * RB;

  // ---------- Phase A: load x, write g*x (bf16) transposed, wave partial sums ----------
  float v[RB];
  #pragma unroll
  for (int r = 0; r < RB; ++r)
    v[r] = x[(r0 + r) * FDIM + tid];       // coalesced per row

  const float g = norm_w[tid];

  float p[RB];
  #pragma unroll
  for (int r = 0; r < RB; ++r) p[r] = v[r] * v[r];
  #pragma unroll
  for (int s = 1; s < 64; s <<= 1) {
    #pragma unroll
    for (int r = 0; r < RB; ++r) p[r] += __shfl_xor(p[r], s, 64);
  }
  if (lane < RB) red[wid * RB + lane] = p[lane];  // red[w*8 + row]

  {
    uint4 h;
    h.x = pack2bf(g * v[0], g * v[1]);
    h.y = pack2bf(g * v[2], g * v[3]);
    h.z = pack2bf(g * v[4], g * v[5]);
    h.w = pack2bf(g * v[6], g * v[7]);
    h_lds[swz((unsigned)tid)] = h;         // conflict-free under swz
  }
  __syncthreads();                          // barrier #1 (granules + partials ready)

  // ---------- redundant per-wave cross-wave reduce: rs for all 8 rows, no 2nd barrier ----------
  float rs[RB];
  {
    float a = red[lane] + red[64 + lane];   // w = lane>>3 and 8+(lane>>3), row = lane&7
    a += __shfl_xor(a, 8, 64);
    a += __shfl_xor(a, 16, 64);
    a += __shfl_xor(a, 32, 64);
    float rsl = rsqrtf(a * (1.0f / FDIM) + EPSV);
    #pragma unroll
    for (int r = 0; r < RB; ++r) rs[r] = __shfl(rsl, (lane & ~7) | r, 64);
  }

  const int o = tid;

  // ---------- Stage 1: acc = gather(g*x)·w1 ; z = rs*acc + b1 ; s = sine(z) ----------
  float acc[RB] = {0.f, 0.f, 0.f, 0.f, 0.f, 0.f, 0.f, 0.f};
  unsigned st2[KNZ];

  if (TR) {
    #pragma unroll
    for (int k = 0; k < KNZ; ++k) {
      uint2 pw = pc[k * FDIM + o];         // coalesced dwordx2, L2-resident
      st2[k] = pw.y;                       // stage-2 (off | w2bf<<16) stays in regs
      float w = __uint_as_float(pw.x & 0xffff0000u);  // bf16 weight in high bits
      uint4 hv = h_lds[pw.x & 1023u];      // ds_read_b128: 8 rows for this (o,k)
      const unsigned int* hd = reinterpret_cast<const unsigned int*>(&hv);
      #pragma unroll
      for (int d = 0; d < 4; ++d) {
        acc[2 * d]     = fmaf(__uint_as_float(hd[d] << 16), w, acc[2 * d]);
        acc[2 * d + 1] = fmaf(__uint_as_float(hd[d] & 0xffff0000u), w, acc[2 * d + 1]);
      }
    }
  } else {
    #pragma unroll 8
    for (int k = 0; k < KNZ; ++k) {
      unsigned off = swz((unsigned)idx[o * KNZ + k]);
      st2[k] = off;
      float w = w1[o * KNZ + k];
      uint4 hv = h_lds[off];
      const unsigned int* hd = reinterpret_cast<const unsigned int*>(&hv);
      #pragma unroll
      for (int d = 0; d < 4; ++d) {
        acc[2 * d]     = fmaf(__uint_as_float(hd[d] << 16), w, acc[2 * d]);
        acc[2 * d + 1] = fmaf(__uint_as_float(hd[d] & 0xffff0000u), w, acc[2 * d + 1]);
      }
    }
  }

  {
    const float bb = b1[o], am = amp[o], fq = freq[o], dc = decay[o];
    float s[RB];
    #pragma unroll
    for (int r = 0; r < RB; ++r) {
      float z = fmaf(acc[r], rs[r], bb);   // rs applied here, off the gather path
      s[r] = am * __sinf(fq * z) * __expf(-dc * z * z);
    }
    uint4 sv;
    sv.x = pack2bf(s[0], s[1]);
    sv.y = pack2bf(s[2], s[3]);
    sv.z = pack2bf(s[4], s[5]);
    sv.w = pack2bf(s[6], s[7]);
    s_lds[swz((unsigned)o)] = sv;          // conflict-free under swz
  }
  __syncthreads();                          // barrier #2

  // ---------- Stage 2: h2 = gather(s)·w2 + b2 ; out = x + alpha*h2 ----------
  #pragma unroll
  for (int r = 0; r < RB; ++r) acc[r] = 0.f;
  if (TR) {
    #pragma unroll
    for (int k = 0; k < KNZ; ++k) {
      unsigned pw = st2[k];                // no global loads in stage 2
      float w = __uint_as_float(pw & 0xffff0000u);
      uint4 sv = s_lds[pw & 1023u];
      const unsigned int* sd = reinterpret_cast<const unsigned int*>(&sv);
      #pragma unroll
      for (int d = 0; d < 4; ++d) {
        acc[2 * d]     = fmaf(__uint_as_float(sd[d] << 16), w, acc[2 * d]);
        acc[2 * d + 1] = fmaf(__uint_as_float(sd[d] & 0xffff0000u), w, acc[2 * d + 1]);
      }
    }
  } else {
    #pragma unroll 8
    for (int k = 0; k < KNZ; ++k) {
      unsigned off = st2[k];
      float w = w2[o * KNZ + k];
      uint4 sv = s_lds[off];
      const unsigned int* sd = reinterpret_cast<const unsigned int*>(&sv);
      #pragma unroll
      for (int d = 0; d < 4; ++d) {
        acc[2 * d]     = fmaf(__uint_as_float(sd[d] << 16), w, acc[2 * d]);
        acc[2 * d + 1] = fmaf(__uint_as_float(sd[d] & 0xffff0000u), w, acc[2 * d + 1]);
      }
    }
  }

  {
    const float bb = b2[o];
    const float al = alpha[0];
    #pragma unroll
    for (int r = 0; r < RB; ++r)
      out[(r0 + r) * FDIM + o] = fmaf(al, acc[r] + bb, v[r]);  // v[r] = x, in regs
  }
}

extern "C" void kernel_launch(void* const* d_in, const int* in_sizes, int n_in,
                              void* d_out, int out_size, void* d_ws, size_t ws_size,
                              hipStream_t stream) {
  const float* x      = (const float*)d_in[0];
  const int*   idx    = (const int*)d_in[1];
  const float* norm_w = (const float*)d_in[2];
  const float* w1     = (const float*)d_in[3];
  const float* b1     = (const float*)d_in[4];
  const float* amp    = (const float*)d_in[5];
  const float* freq   = (const float*)d_in[6];
  const float* decay  = (const float*)d_in[7];
  const float* w2     = (const float*)d_in[8];
  const float* b2     = (const float*)d_in[9];
  const float* alpha  = (const float*)d_in[10];
  float* out = (float*)d_out;

  const size_t need = (size_t)FDIM * KNZ * sizeof(uint2);  // 256 KB
  if (ws_size >= need) {
    uint2* pc = (uint2*)d_ws;
    geo_prep<<<FDIM / 16, 256, 0, stream>>>(idx, w1, w2, pc);
    geo_main<true><<<NROWS / RB, TPB, 0, stream>>>(
        x, norm_w, b1, amp, freq, decay, b2, alpha, pc, idx, w1, w2, out);
  } else {
    geo_main<false><<<NROWS / RB, TPB, 0, stream>>>(
        x, norm_w, b1, amp, freq, decay, b2, alpha, nullptr, idx, w1, w2, out);
  }
}